// Round 1
// baseline (963.866 us; speedup 1.0000x reference)
//
#include <hip/hip_runtime.h>
#include <hip/hip_bf16.h>

// Problem: out[b, n*128+o] = sum_m x[b, n*128+m] * softmax_m(c[n, m, o])
// B=2048, N_BLOCKS=512, BLOCK_IN=BLOCK_OUT=128, LAYER=65536.
// Memory-bound: ~1.06 GB mandatory traffic (x 512MB + out 512MB + c/w ~50MB)
// -> ~170us floor at 6.3 TB/s achievable. NOTE: bench dur_us includes harness
// re-poison fills (~345us each, seen in rocprof top-5); kernel-side budget is
// only the remainder.

#define N_BLOCKS 512
#define BI 128
#define BO 128
#define LAYER 65536
#define BATCH 2048

typedef __bf16 bf16x4_t __attribute__((ext_vector_type(4)));
typedef __bf16 bf16x8_t __attribute__((ext_vector_type(8)));
typedef float floatx16_t __attribute__((ext_vector_type(16)));

// ---------------------------------------------------------------------------
// Kernel 1: column softmax over m of c[n][m][o], write TRANSPOSED bf16
// w[n][o][m] so that K (=m) is contiguous for the GEMM's B-fragment reads.
// Wave-per-column, shuffle reductions; verified correct previously. ~10us,
// not the bottleneck -> unchanged this round.
// ---------------------------------------------------------------------------
__global__ __launch_bounds__(256) void softmax_kernel(
    const float* __restrict__ c, __bf16* __restrict__ w) {
  const int n = blockIdx.x;
  const int t = threadIdx.x;
  const int wv = t >> 6;
  const int lane = t & 63;
  const float* cb = c + (size_t)n * (BI * BO);
  __bf16* wb = w + (size_t)n * (BO * BI);

  for (int i = 0; i < 32; ++i) {
    const int o = wv * 32 + i;  // this wave's column
    // lane l holds rows m = l and m = l+64 of column o
    float v0 = cb[lane * BO + o];
    float v1 = cb[(lane + 64) * BO + o];
    float mx = fmaxf(v0, v1);
#pragma unroll
    for (int d = 1; d < 64; d <<= 1) mx = fmaxf(mx, __shfl_xor(mx, d, 64));
    float e0 = __expf(v0 - mx);
    float e1 = __expf(v1 - mx);
    float s = e0 + e1;
#pragma unroll
    for (int d = 1; d < 64; d <<= 1) s += __shfl_xor(s, d, 64);
    float inv = 1.0f / s;
    // transposed store: w[n][o][m], lanes write consecutive bf16 -> coalesced
    wb[o * BI + lane] = (__bf16)(e0 * inv);
    wb[o * BI + lane + 64] = (__bf16)(e1 * inv);
  }
}

// ---------------------------------------------------------------------------
// Kernel 2: per-block GEMM [2048x128] @ [128x128] using mfma_f32_32x32x16_bf16.
// WG = 256 threads (4 waves). Output tile 128(M) x 128(O) per WG.
//
// This round's change vs the 916us version:
//  * x (A operand) no longer staged through LDS. A-fragment rows are private
//    to each wave (row = wv*32 + (lane&31)), so each lane loads its 8-float
//    k-chunks straight from global into registers and converts to bf16.
//    Removes a 64KB LDS write+read round trip per WG and halves LDS to 32KB.
//  * LDS 64KB->32KB and __launch_bounds__(256,3): 2 -> 3 WGs/CU, more
//    cross-WG phase overlap for this memory-bound kernel. Staging regs and
//    the 64 acc regs are not simultaneously live, so no spill expected.
//  * Bijective XCD swizzle (8192 WGs % 8 == 0): XCD k owns n in
//    [k*64, (k+1)*64) -> its 2MB w slice stays resident in its private L2,
//    and the 16 mb-WGs per n are temporally adjacent on one XCD.
// ---------------------------------------------------------------------------
__global__ __launch_bounds__(256, 3) void gemm_kernel(
    const float* __restrict__ x, const __bf16* __restrict__ w,
    float* __restrict__ out) {
  __shared__ __align__(16) __bf16 ws_[128 * 16 * 8];  // 32 KB, [o][chunk^swz][8]

  // XCD-aware bijective swizzle: orig%8 ~ XCD (round-robin dispatch heuristic)
  const int orig = blockIdx.y * gridDim.x + blockIdx.x;
  const int wgid = ((orig & 7) << 10) | (orig >> 3);  // 8192 = 8 * 1024
  const int n = wgid >> 4;
  const int m_base = (wgid & 15) << 7;

  const int t = threadIdx.x;
  const int wv = t >> 6;
  const int lane = t & 63;
  const int lr = lane & 31;
  const int half = lane >> 5;

  // ---- stage w tile: 128x128 bf16 (8 x 16B loads per thread) ----
  // Issued first: these feed the barrier everyone waits on.
  {
    const __bf16* wg = w + (size_t)n * (BO * BI);
#pragma unroll
    for (int i = 0; i < 8; ++i) {
      int lin = t + i * 256;          // 16B chunk index within tile
      int o = lin >> 4;
      int mc = lin & 15;              // chunk along m
      bf16x8_t v = *(const bf16x8_t*)(wg + o * BI + mc * 8);
      int chunk = mc ^ (o & 15);      // XOR swizzle: conflict-free b128 reads
      *(bf16x8_t*)&ws_[(o * 16 + chunk) * 8] = v;
    }
  }

  // ---- A fragments: direct global->register, fp32 -> bf16 in-reg ----
  // A-frag layout for mfma_32x32x16: row = lane&31 (+wv*32), k = half*8 + j
  // per k-step of 16. Per step the wave consumes full 64B lines (half 0/1
  // cover adjacent 32B), so no HBM over-fetch.
  bf16x8_t af[8];
  {
    const float* xg =
        x + (size_t)(m_base + wv * 32 + lr) * LAYER + n * BI + half * 8;
#pragma unroll
    for (int s = 0; s < 8; ++s) {
      float4 v0 = *(const float4*)(xg + s * 16);
      float4 v1 = *(const float4*)(xg + s * 16 + 4);
      bf16x8_t a;
      a[0] = (__bf16)v0.x; a[1] = (__bf16)v0.y;
      a[2] = (__bf16)v0.z; a[3] = (__bf16)v0.w;
      a[4] = (__bf16)v1.x; a[5] = (__bf16)v1.y;
      a[6] = (__bf16)v1.z; a[7] = (__bf16)v1.w;
      af[s] = a;
    }
  }
  __syncthreads();

  floatx16_t acc[4];
#pragma unroll
  for (int nt = 0; nt < 4; ++nt)
#pragma unroll
    for (int r = 0; r < 16; ++r) acc[nt][r] = 0.0f;

  // K = 128: 8 MFMA steps of k=16. B from LDS (shared by all 4 waves).
#pragma unroll
  for (int step = 0; step < 8; ++step) {
    const int kc = step * 2 + half;  // 8-elem chunk index along K
#pragma unroll
    for (int nt = 0; nt < 4; ++nt) {
      int ocol = nt * 32 + lr;       // B fragment col
      bf16x8_t b =
          *(const bf16x8_t*)&ws_[(ocol * 16 + (kc ^ (ocol & 15))) * 8];
      acc[nt] =
          __builtin_amdgcn_mfma_f32_32x32x16_bf16(af[step], b, acc[nt], 0, 0, 0);
    }
  }

  // ---- epilogue: measured C/D mapping col=lane&31, row=(r&3)+8*(r>>2)+4*half
  float* og = out + (size_t)(m_base + wv * 32) * LAYER + n * BO;
#pragma unroll
  for (int nt = 0; nt < 4; ++nt) {
#pragma unroll
    for (int r = 0; r < 16; ++r) {
      int row = (r & 3) + 8 * (r >> 2) + 4 * half;
      og[(size_t)row * LAYER + nt * 32 + lr] = acc[nt][r];
    }
  }
}

extern "C" void kernel_launch(void* const* d_in, const int* in_sizes, int n_in,
                              void* d_out, int out_size, void* d_ws,
                              size_t ws_size, hipStream_t stream) {
  const float* x = (const float*)d_in[0];   // [2048, 65536]
  const float* c = (const float*)d_in[1];   // [512, 128, 128]
  float* out = (float*)d_out;               // [2048, 65536]
  __bf16* w = (__bf16*)d_ws;                // [512, 128, 128] bf16, [n][o][m]

  softmax_kernel<<<dim3(N_BLOCKS), dim3(256), 0, stream>>>(c, w);
  gemm_kernel<<<dim3(BATCH / 128, N_BLOCKS), dim3(256), 0, stream>>>(x, w, out);
}